// Round 7
// baseline (1585.786 us; speedup 1.0000x reference)
//
#include <hip/hip_runtime.h>

// DIMKT forward. B=512, S=200, E=128.
// dimkt_prep: 158 blocks x 256 thr; table rows folded through W halves.
//   ws layout (floats): C1=0, SD1=131200, SD6=144256, A4=157312, A5=157568,
//   A6=157824.
// dimkt_scan: 512 blocks x 512 thr, ONE batch row per block -> guaranteed
//   2 blocks/CU (independent barrier domains fill each other's latency) and
//   4 waves/SIMD. A-tile rows: {0}=qq, {1}=k (stage1; v2,v3 in D reg0, v6 in
//   D reg1, all real in quad 0), {0}=sdf (stage2). Weights resident as VGPR
//   B-frags. Exec-masked frag reads (l15<2 / l15==0) with persistent zero
//   frags; stores + table gathers masked to q0 (sole consumers). Loop has no
//   global vmem except q0-masked gathers; indices LDS-preloaded; outputs
//   LDS-buffered. 2 barriers/step.

#define S_ 200
#define E_ 128
#define RS 136   // halves per LDS row

typedef float  float4v __attribute__((ext_vector_type(4)));
typedef _Float16 f16x8 __attribute__((ext_vector_type(8)));

__device__ __forceinline__ float fast_sigmoid(float x) {
  return __builtin_amdgcn_rcpf(1.f + __expf(-x));
}
__device__ __forceinline__ float fast_tanh(float x) {
  return 2.f * __builtin_amdgcn_rcpf(1.f + __expf(-2.f * x)) - 1.f;
}

// x + row_shr:<ctrl> shifted x (bound_ctrl: zeros in); sum lands in lane15 of each 16-row
#define DPP_ADD(x, ctrl) \
  ((x) + __builtin_bit_cast(float, __builtin_amdgcn_update_dpp( \
       0, __builtin_bit_cast(int, (x)), (ctrl), 0xf, 0xf, true)))

__device__ __forceinline__ f16x8 cvt8(const float* __restrict__ p) {
  float4v a = *(const float4v*)p;
  float4v b = *(const float4v*)(p + 4);
  f16x8 r;
  r[0] = (_Float16)a[0]; r[1] = (_Float16)a[1];
  r[2] = (_Float16)a[2]; r[3] = (_Float16)a[3];
  r[4] = (_Float16)b[0]; r[5] = (_Float16)b[1];
  r[6] = (_Float16)b[2]; r[7] = (_Float16)b[3];
  return r;
}

// ---------------- prep: 8 rows/block, coalesced LDS-staged W ----------------
__global__ __launch_bounds__(256) void dimkt_prep(
    const float* __restrict__ c_table, const float* __restrict__ sd_table,
    const float* __restrict__ a_table,
    const float* __restrict__ W1, const float* __restrict__ b1,
    const float* __restrict__ W4, const float* __restrict__ b4,
    const float* __restrict__ W5, const float* __restrict__ b5,
    const float* __restrict__ W6, const float* __restrict__ b6,
    float* __restrict__ ws) {
  __shared__ __attribute__((aligned(16))) float s_src[8][E_];
  __shared__ float s_w[E_][33];
  const int blk = blockIdx.x, t = threadIdx.x;
  const int e = t & 127, h = t >> 7;
  const float* src; const float* wb; const float* bias; float* dst;
  int r0, maxrow, wstr, woff;
  if (blk < 129)      { r0 = blk * 8;       src = c_table;  maxrow = 1024; wb = W1; wstr = 256; woff = 0;   bias = nullptr; dst = ws; }
  else if (blk < 142) { r0 = (blk-129) * 8; src = sd_table; maxrow = 101;  wb = W1; wstr = 256; woff = 128; bias = b1;      dst = ws + 131200; }
  else if (blk < 155) { r0 = (blk-142) * 8; src = sd_table; maxrow = 101;  wb = W6; wstr = 384; woff = 256; bias = nullptr; dst = ws + 144256; }
  else if (blk == 155){ r0 = 0;             src = a_table;  maxrow = 1;    wb = W4; wstr = 256; woff = 128; bias = b4;      dst = ws + 157312; }
  else if (blk == 156){ r0 = 0;             src = a_table;  maxrow = 1;    wb = W5; wstr = 256; woff = 128; bias = b5;      dst = ws + 157568; }
  else                { r0 = 0;             src = a_table;  maxrow = 1;    wb = W6; wstr = 384; woff = 128; bias = b6;      dst = ws + 157824; }
  #pragma unroll
  for (int i = 0; i < 4; ++i) {
    int idx = i * 256 + t, row = idx >> 7, col = idx & 127;
    int rr = r0 + row; if (rr > maxrow) rr = maxrow;
    s_src[row][col] = src[rr * E_ + col];
  }
  float binit = bias ? bias[e] : 0.f;
  float acc[4] = {binit, binit, binit, binit};
  for (int k0 = 0; k0 < 4; ++k0) {
    __syncthreads();                 // first: s_src ready; later: s_w reuse safe
    #pragma unroll
    for (int i = 0; i < 16; ++i) {
      int idx = i * 256 + t;
      s_w[idx >> 5][idx & 31] = wb[(idx >> 5) * wstr + woff + k0 * 32 + (idx & 31)];
    }
    __syncthreads();
    #pragma unroll 4
    for (int kk = 0; kk < 32; ++kk) {
      float wv = s_w[e][kk];
      #pragma unroll
      for (int g = 0; g < 4; ++g)
        acc[g] += wv * s_src[h * 4 + g][k0 * 32 + kk];
    }
  }
  #pragma unroll
  for (int g = 0; g < 4; ++g) {
    int row = r0 + h * 4 + g;
    if (row <= maxrow) dst[row * E_ + e] = acc[g];
  }
}

// ---------------- the scan: 512 blocks, 1 batch row each ----------------
__global__ __launch_bounds__(512, 4) void dimkt_scan(
    const int* __restrict__ c, const int* __restrict__ sd, const int* __restrict__ a,
    const int* __restrict__ cshft, const int* __restrict__ sdshft,
    const float* __restrict__ knowledge,
    const float* __restrict__ W2, const float* __restrict__ b2,
    const float* __restrict__ W3, const float* __restrict__ b3,
    const float* __restrict__ W4, const float* __restrict__ W5,
    const float* __restrict__ W6,
    const float* __restrict__ ws, float* __restrict__ out) {

  const float* __restrict__ C1  = ws;
  const float* __restrict__ SD1 = ws + 131200;
  const float* __restrict__ SD6 = ws + 144256;
  const float* __restrict__ A4  = ws + 157312;
  const float* __restrict__ A5  = ws + 157568;
  const float* __restrict__ A6  = ws + 157824;

  const int tid  = threadIdx.x;
  const int w    = tid >> 6;        // wave 0..7 -> E-slice [16w, 16w+16)
  const int lane = tid & 63;
  const int l15  = lane & 15;
  const int q    = lane >> 4;       // quad 0..3
  const int e    = w * 16 + l15;    // output column this lane owns
  const int bj   = blockIdx.x;      // the single batch row

  __shared__ __attribute__((aligned(16))) _Float16 A1[2 * RS];  // row0=qq, row1=k
  __shared__ __attribute__((aligned(16))) _Float16 A2[RS];      // row0=sdf
  __shared__ __attribute__((aligned(32))) int idx_lds[S_][8];
  __shared__ float olog[S_];
  __shared__ float red[8];

  // one-time coalesced index preload
  for (int i = tid; i < S_; i += 512) {
    const int src = bj * S_ + i;
    idx_lds[i][0] = c[src];
    idx_lds[i][1] = sd[src];
    idx_lds[i][2] = a[src];
    idx_lds[i][3] = cshft[src];
    idx_lds[i][4] = sdshft[src];
  }

  const int rd0 = l15 * RS + q * 8;   // A-frag read base (halves), +32*t per frag
  const bool m1 = (l15 < 2);          // stage-1 rows {0,1}
  const bool m2 = (l15 == 0);         // stage-2 row  {0}
  const bool st = (q == 0);           // store / gather-owner lanes

  // Weight B-fragments: lane holds W[e][32t + 8q + 0..7]
  f16x8 w2f[4], w3f[4], w4f[4], w5f[4], w6f[4];
  #pragma unroll
  for (int t = 0; t < 4; ++t) {
    const int ko = t * 32 + q * 8;
    w2f[t] = cvt8(W2 + e * 128 + ko);
    w3f[t] = cvt8(W3 + e * 128 + ko);
    w4f[t] = cvt8(W4 + e * 256 + ko);   // first E cols
    w5f[t] = cvt8(W5 + e * 256 + ko);
    w6f[t] = cvt8(W6 + e * 384 + ko);   // k third of W6
  }
  const float b2e = b2[e], b3e = b3[e];
  const float A4t0 = A4[e], A4t1 = A4[E_ + e];
  const float A5t0 = A5[e], A5t1 = A5[E_ + e];
  const float A6t0 = A6[e], A6t1 = A6[E_ + e];

  float kreg = knowledge[e];

  // pre-loop gathers (outside steady loop; all lanes fine)
  const int base = bj * S_;
  int ic = c[base], isd = sd[base], ia = a[base], ict = cshft[base], ist = sdshft[base];
  float inT  = C1[ic * E_ + e] + SD1[isd * E_ + e];
  float sd6v = SD6[isd * E_ + e];
  float a4v = ia ? A4t1 : A4t0;
  float a5v = ia ? A5t1 : A5t0;
  float a6v = ia ? A6t1 : A6t0;
  float tgt  = C1[ict * E_ + e] + SD1[ist * E_ + e];
  int nic = c[base + 1], nisd = sd[base + 1], nia = a[base + 1],
      nict = cshft[base + 1], nist = sdshft[base + 1];

  __syncthreads();                         // idx preload visible
  if (st) {
    A1[e]      = (_Float16)(kreg - inT);   // row 0: qq
    A1[RS + e] = (_Float16)kreg;           // row 1: k
  }
  __syncthreads();                         // initial A1 staged

  // persistent zero frags: masked-out lanes never write them -> stay 0
  f16x8 f0{}, f1{}, f2{}, f3{};
  f16x8 g0{}, g1{}, g2v{}, g3{};

  // persistent accumulators; unused regs carry bounded stale values.
  float4v acc2{0.f,0.f,0.f,0.f}, acc3{0.f,0.f,0.f,0.f}, acc6{0.f,0.f,0.f,0.f};
  float4v acc4{0.f,0.f,0.f,0.f}, acc5{0.f,0.f,0.f,0.f};

  float ninT = inT, nsd6 = sd6v, na4 = a4v, na5 = a5v, na6 = a6v, ntg = tgt;

  #pragma unroll 1
  for (int s = 0; s < S_; ++s) {
    // ---- stage 1: frags feed W2,W3 (qq row 0) and W6 (k row 1) ----
    if (m1) {
      f0 = *(const f16x8*)&A1[rd0];
      f1 = *(const f16x8*)&A1[rd0 + 32];
      f2 = *(const f16x8*)&A1[rd0 + 64];
      f3 = *(const f16x8*)&A1[rd0 + 96];
    }

    // next step's table gathers + s+2 idx: only q0 consumes them -> masked
    const int s2 = (s + 2 < S_) ? (s + 2) : (S_ - 1);
    if (st) {
      ninT = C1[nic * E_ + e] + SD1[nisd * E_ + e];
      nsd6 = SD6[nisd * E_ + e];
      na4 = nia ? A4t1 : A4t0;
      na5 = nia ? A5t1 : A5t0;
      na6 = nia ? A6t1 : A6t0;
      ntg  = C1[nict * E_ + e] + SD1[nist * E_ + e];
      const int4 iv = *(const int4*)&idx_lds[s2][0];
      nic = iv.x; nisd = iv.y; nia = iv.z; nict = iv.w;
      nist = idx_lds[s2][4];
    }

    acc2[0] = b2e;
    acc3[0] = b3e;
    acc6[1] = a6v + sd6v;                 // k row 1 -> D reg1
    acc2 = __builtin_amdgcn_mfma_f32_16x16x32_f16(f0, w2f[0], acc2, 0, 0, 0);
    acc3 = __builtin_amdgcn_mfma_f32_16x16x32_f16(f0, w3f[0], acc3, 0, 0, 0);
    acc6 = __builtin_amdgcn_mfma_f32_16x16x32_f16(f0, w6f[0], acc6, 0, 0, 0);
    acc2 = __builtin_amdgcn_mfma_f32_16x16x32_f16(f1, w2f[1], acc2, 0, 0, 0);
    acc3 = __builtin_amdgcn_mfma_f32_16x16x32_f16(f1, w3f[1], acc3, 0, 0, 0);
    acc6 = __builtin_amdgcn_mfma_f32_16x16x32_f16(f1, w6f[1], acc6, 0, 0, 0);
    acc2 = __builtin_amdgcn_mfma_f32_16x16x32_f16(f2, w2f[2], acc2, 0, 0, 0);
    acc3 = __builtin_amdgcn_mfma_f32_16x16x32_f16(f2, w3f[2], acc3, 0, 0, 0);
    acc6 = __builtin_amdgcn_mfma_f32_16x16x32_f16(f2, w6f[2], acc6, 0, 0, 0);
    acc2 = __builtin_amdgcn_mfma_f32_16x16x32_f16(f3, w2f[3], acc2, 0, 0, 0);
    acc3 = __builtin_amdgcn_mfma_f32_16x16x32_f16(f3, w3f[3], acc3, 0, 0, 0);
    acc6 = __builtin_amdgcn_mfma_f32_16x16x32_f16(f3, w6f[3], acc6, 0, 0, 0);

    // real values in quad 0 (row0 -> reg0, row1 -> reg1)
    const float g2  = fast_sigmoid(acc2[0]);
    const float th3 = fast_tanh(acc3[0]);
    const float g6  = fast_sigmoid(acc6[1]);
    const float sdfv = g2 * th3;
    if (st) A2[e] = (_Float16)sdfv;
    __syncthreads();                          // B1: sdf staged

    // ---- stage 2: W4, W5 on sdf (row 0 only) ----
    if (m2) {
      g0  = *(const f16x8*)&A2[rd0];
      g1  = *(const f16x8*)&A2[rd0 + 32];
      g2v = *(const f16x8*)&A2[rd0 + 64];
      g3  = *(const f16x8*)&A2[rd0 + 96];
    }

    acc4[0] = a4v;
    acc5[0] = a5v;
    acc4 = __builtin_amdgcn_mfma_f32_16x16x32_f16(g0, w4f[0], acc4, 0, 0, 0);
    acc5 = __builtin_amdgcn_mfma_f32_16x16x32_f16(g0, w5f[0], acc5, 0, 0, 0);
    acc4 = __builtin_amdgcn_mfma_f32_16x16x32_f16(g1, w4f[1], acc4, 0, 0, 0);
    acc5 = __builtin_amdgcn_mfma_f32_16x16x32_f16(g1, w5f[1], acc5, 0, 0, 0);
    acc4 = __builtin_amdgcn_mfma_f32_16x16x32_f16(g2v, w4f[2], acc4, 0, 0, 0);
    acc5 = __builtin_amdgcn_mfma_f32_16x16x32_f16(g2v, w5f[2], acc5, 0, 0, 0);
    acc4 = __builtin_amdgcn_mfma_f32_16x16x32_f16(g3, w4f[3], acc4, 0, 0, 0);
    acc5 = __builtin_amdgcn_mfma_f32_16x16x32_f16(g3, w5f[3], acc5, 0, 0, 0);

    const float pka  = fast_sigmoid(acc4[0]) * fast_tanh(acc5[0]);  // real in q0
    const float knew = pka + g6 * (kreg - pka);
    kreg = knew;
    if (st) {
      A1[e]      = (_Float16)(knew - ninT);   // next qq
      A1[RS + e] = (_Float16)knew;            // next k
    }

    // fused logit: dot(target, knew); DPP sum -> lane15 of each quad (q0 real)
    float p = tgt * knew;
    p = DPP_ADD(p, 0x111);
    p = DPP_ADD(p, 0x112);
    p = DPP_ADD(p, 0x114);
    p = DPP_ADD(p, 0x118);
    if (l15 == 15 && q == 0) red[w] = p;

    inT = ninT; sd6v = nsd6; a4v = na4; a5v = na5; a6v = na6; tgt = ntg;

    __syncthreads();                          // B2: A1' + red visible

    if (tid == 0) {
      float logit = 0.f;
      #pragma unroll
      for (int x = 0; x < 8; ++x) logit += red[x];
      olog[s] = fast_sigmoid(logit);
    }
  }

  // single coalesced output flush
  __syncthreads();
  for (int i = tid; i < S_; i += 512) out[bj * S_ + i] = olog[i];
}

extern "C" void kernel_launch(void* const* d_in, const int* in_sizes, int n_in,
                              void* d_out, int out_size, void* d_ws, size_t ws_size,
                              hipStream_t stream) {
  const int*   c         = (const int*)  d_in[0];
  const int*   sd        = (const int*)  d_in[1];
  const int*   a         = (const int*)  d_in[2];
  const int*   cshft     = (const int*)  d_in[3];
  const int*   sdshft    = (const int*)  d_in[4];
  const float* c_table   = (const float*)d_in[5];
  const float* sd_table  = (const float*)d_in[6];
  const float* a_table   = (const float*)d_in[7];
  const float* knowledge = (const float*)d_in[8];
  const float* W1 = (const float*)d_in[9];  const float* b1 = (const float*)d_in[10];
  const float* W2 = (const float*)d_in[11]; const float* b2 = (const float*)d_in[12];
  const float* W3 = (const float*)d_in[13]; const float* b3 = (const float*)d_in[14];
  const float* W4 = (const float*)d_in[15]; const float* b4 = (const float*)d_in[16];
  const float* W5 = (const float*)d_in[17]; const float* b5 = (const float*)d_in[18];
  const float* W6 = (const float*)d_in[19]; const float* b6 = (const float*)d_in[20];
  float* ws  = (float*)d_ws;
  float* out = (float*)d_out;
  (void)in_sizes; (void)n_in; (void)out_size; (void)ws_size;

  dimkt_prep<<<158, 256, 0, stream>>>(c_table, sd_table, a_table,
                                      W1, b1, W4, b4, W5, b5, W6, b6, ws);
  dimkt_scan<<<512, 512, 0, stream>>>(c, sd, a, cshft, sdshft, knowledge,
                                      W2, b2, W3, b3, W4, W5, W6, ws, out);
}

// Round 8
// 490.416 us; speedup vs baseline: 3.2336x; 3.2336x over previous
//
#include <hip/hip_runtime.h>

// DIMKT forward. B=512, S=200, E=128.
// dimkt_prep: 158 blocks x 256 thr; table rows folded through W halves.
//   ws layout (floats): C1=0, SD1=131200, SD6=144256, A4=157312, A5=157568,
//   A6=157824.
// dimkt_scan: 512 blocks x 512 thr, ONE batch row per block; 2 blocks/CU
//   co-resident (independent barrier domains fill each other's latency).
//   NOTE: __launch_bounds__(512, 2) NOT (512,4) — the latter caps VGPR at 64
//   and spills the 80-VGPR resident weight frags to scratch (r7: 5 GB traffic).
//   At ~100 VGPR the HW still fits 16 waves/CU = 2 blocks.
//   A-tile rows: {0}=qq, {1}=k (stage1; v2,v3 in D reg0, v6 in D reg1, all
//   real in quad 0), {0}=sdf (stage2). Weights resident as VGPR B-frags.
//   Exec-masked frag reads with persistent zero frags; stores + table gathers
//   masked to q0. Loop has no global vmem except q0-masked gathers; indices
//   LDS-preloaded; outputs LDS-buffered. 2 barriers/step.

#define S_ 200
#define E_ 128
#define RS 136   // halves per LDS row

typedef float  float4v __attribute__((ext_vector_type(4)));
typedef _Float16 f16x8 __attribute__((ext_vector_type(8)));

__device__ __forceinline__ float fast_sigmoid(float x) {
  return __builtin_amdgcn_rcpf(1.f + __expf(-x));
}
__device__ __forceinline__ float fast_tanh(float x) {
  return 2.f * __builtin_amdgcn_rcpf(1.f + __expf(-2.f * x)) - 1.f;
}

// x + row_shr:<ctrl> shifted x (bound_ctrl: zeros in); sum lands in lane15 of each 16-row
#define DPP_ADD(x, ctrl) \
  ((x) + __builtin_bit_cast(float, __builtin_amdgcn_update_dpp( \
       0, __builtin_bit_cast(int, (x)), (ctrl), 0xf, 0xf, true)))

__device__ __forceinline__ f16x8 cvt8(const float* __restrict__ p) {
  float4v a = *(const float4v*)p;
  float4v b = *(const float4v*)(p + 4);
  f16x8 r;
  r[0] = (_Float16)a[0]; r[1] = (_Float16)a[1];
  r[2] = (_Float16)a[2]; r[3] = (_Float16)a[3];
  r[4] = (_Float16)b[0]; r[5] = (_Float16)b[1];
  r[6] = (_Float16)b[2]; r[7] = (_Float16)b[3];
  return r;
}

// ---------------- prep: 8 rows/block, coalesced LDS-staged W ----------------
__global__ __launch_bounds__(256) void dimkt_prep(
    const float* __restrict__ c_table, const float* __restrict__ sd_table,
    const float* __restrict__ a_table,
    const float* __restrict__ W1, const float* __restrict__ b1,
    const float* __restrict__ W4, const float* __restrict__ b4,
    const float* __restrict__ W5, const float* __restrict__ b5,
    const float* __restrict__ W6, const float* __restrict__ b6,
    float* __restrict__ ws) {
  __shared__ __attribute__((aligned(16))) float s_src[8][E_];
  __shared__ float s_w[E_][33];
  const int blk = blockIdx.x, t = threadIdx.x;
  const int e = t & 127, h = t >> 7;
  const float* src; const float* wb; const float* bias; float* dst;
  int r0, maxrow, wstr, woff;
  if (blk < 129)      { r0 = blk * 8;       src = c_table;  maxrow = 1024; wb = W1; wstr = 256; woff = 0;   bias = nullptr; dst = ws; }
  else if (blk < 142) { r0 = (blk-129) * 8; src = sd_table; maxrow = 101;  wb = W1; wstr = 256; woff = 128; bias = b1;      dst = ws + 131200; }
  else if (blk < 155) { r0 = (blk-142) * 8; src = sd_table; maxrow = 101;  wb = W6; wstr = 384; woff = 256; bias = nullptr; dst = ws + 144256; }
  else if (blk == 155){ r0 = 0;             src = a_table;  maxrow = 1;    wb = W4; wstr = 256; woff = 128; bias = b4;      dst = ws + 157312; }
  else if (blk == 156){ r0 = 0;             src = a_table;  maxrow = 1;    wb = W5; wstr = 256; woff = 128; bias = b5;      dst = ws + 157568; }
  else                { r0 = 0;             src = a_table;  maxrow = 1;    wb = W6; wstr = 384; woff = 128; bias = b6;      dst = ws + 157824; }
  #pragma unroll
  for (int i = 0; i < 4; ++i) {
    int idx = i * 256 + t, row = idx >> 7, col = idx & 127;
    int rr = r0 + row; if (rr > maxrow) rr = maxrow;
    s_src[row][col] = src[rr * E_ + col];
  }
  float binit = bias ? bias[e] : 0.f;
  float acc[4] = {binit, binit, binit, binit};
  for (int k0 = 0; k0 < 4; ++k0) {
    __syncthreads();                 // first: s_src ready; later: s_w reuse safe
    #pragma unroll
    for (int i = 0; i < 16; ++i) {
      int idx = i * 256 + t;
      s_w[idx >> 5][idx & 31] = wb[(idx >> 5) * wstr + woff + k0 * 32 + (idx & 31)];
    }
    __syncthreads();
    #pragma unroll 4
    for (int kk = 0; kk < 32; ++kk) {
      float wv = s_w[e][kk];
      #pragma unroll
      for (int g = 0; g < 4; ++g)
        acc[g] += wv * s_src[h * 4 + g][k0 * 32 + kk];
    }
  }
  #pragma unroll
  for (int g = 0; g < 4; ++g) {
    int row = r0 + h * 4 + g;
    if (row <= maxrow) dst[row * E_ + e] = acc[g];
  }
}

// ---------------- the scan: 512 blocks, 1 batch row each ----------------
__global__ __launch_bounds__(512, 2) void dimkt_scan(
    const int* __restrict__ c, const int* __restrict__ sd, const int* __restrict__ a,
    const int* __restrict__ cshft, const int* __restrict__ sdshft,
    const float* __restrict__ knowledge,
    const float* __restrict__ W2, const float* __restrict__ b2,
    const float* __restrict__ W3, const float* __restrict__ b3,
    const float* __restrict__ W4, const float* __restrict__ W5,
    const float* __restrict__ W6,
    const float* __restrict__ ws, float* __restrict__ out) {

  const float* __restrict__ C1  = ws;
  const float* __restrict__ SD1 = ws + 131200;
  const float* __restrict__ SD6 = ws + 144256;
  const float* __restrict__ A4  = ws + 157312;
  const float* __restrict__ A5  = ws + 157568;
  const float* __restrict__ A6  = ws + 157824;

  const int tid  = threadIdx.x;
  const int w    = tid >> 6;        // wave 0..7 -> E-slice [16w, 16w+16)
  const int lane = tid & 63;
  const int l15  = lane & 15;
  const int q    = lane >> 4;       // quad 0..3
  const int e    = w * 16 + l15;    // output column this lane owns
  const int bj   = blockIdx.x;      // the single batch row

  __shared__ __attribute__((aligned(16))) _Float16 A1[2 * RS];  // row0=qq, row1=k
  __shared__ __attribute__((aligned(16))) _Float16 A2[RS];      // row0=sdf
  __shared__ __attribute__((aligned(32))) int idx_lds[S_][8];
  __shared__ float olog[S_];
  __shared__ float red[8];

  // one-time coalesced index preload
  for (int i = tid; i < S_; i += 512) {
    const int src = bj * S_ + i;
    idx_lds[i][0] = c[src];
    idx_lds[i][1] = sd[src];
    idx_lds[i][2] = a[src];
    idx_lds[i][3] = cshft[src];
    idx_lds[i][4] = sdshft[src];
  }

  const int rd0 = l15 * RS + q * 8;   // A-frag read base (halves), +32*t per frag
  const bool m1 = (l15 < 2);          // stage-1 rows {0,1}
  const bool m2 = (l15 == 0);         // stage-2 row  {0}
  const bool st = (q == 0);           // store / gather-owner lanes

  // Weight B-fragments: lane holds W[e][32t + 8q + 0..7]  (80 VGPRs resident)
  f16x8 w2f[4], w3f[4], w4f[4], w5f[4], w6f[4];
  #pragma unroll
  for (int t = 0; t < 4; ++t) {
    const int ko = t * 32 + q * 8;
    w2f[t] = cvt8(W2 + e * 128 + ko);
    w3f[t] = cvt8(W3 + e * 128 + ko);
    w4f[t] = cvt8(W4 + e * 256 + ko);   // first E cols
    w5f[t] = cvt8(W5 + e * 256 + ko);
    w6f[t] = cvt8(W6 + e * 384 + ko);   // k third of W6
  }
  const float b2e = b2[e], b3e = b3[e];
  const float A4t0 = A4[e], A4t1 = A4[E_ + e];
  const float A5t0 = A5[e], A5t1 = A5[E_ + e];
  const float A6t0 = A6[e], A6t1 = A6[E_ + e];

  float kreg = knowledge[e];

  // pre-loop gathers (outside steady loop; all lanes fine)
  const int base = bj * S_;
  int ic = c[base], isd = sd[base], ia = a[base], ict = cshft[base], ist = sdshft[base];
  float inT  = C1[ic * E_ + e] + SD1[isd * E_ + e];
  float sd6v = SD6[isd * E_ + e];
  float a4v = ia ? A4t1 : A4t0;
  float a5v = ia ? A5t1 : A5t0;
  float a6v = ia ? A6t1 : A6t0;
  float tgt  = C1[ict * E_ + e] + SD1[ist * E_ + e];
  int nic = c[base + 1], nisd = sd[base + 1], nia = a[base + 1],
      nict = cshft[base + 1], nist = sdshft[base + 1];

  __syncthreads();                         // idx preload visible
  if (st) {
    A1[e]      = (_Float16)(kreg - inT);   // row 0: qq
    A1[RS + e] = (_Float16)kreg;           // row 1: k
  }
  __syncthreads();                         // initial A1 staged

  // persistent zero frags: masked-out lanes never write them -> stay 0
  f16x8 f0{}, f1{}, f2{}, f3{};
  f16x8 g0{}, g1{}, g2v{}, g3{};

  // persistent accumulators; unused regs carry bounded stale values.
  float4v acc2{0.f,0.f,0.f,0.f}, acc3{0.f,0.f,0.f,0.f}, acc6{0.f,0.f,0.f,0.f};
  float4v acc4{0.f,0.f,0.f,0.f}, acc5{0.f,0.f,0.f,0.f};

  float ninT = inT, nsd6 = sd6v, na4 = a4v, na5 = a5v, na6 = a6v, ntg = tgt;

  #pragma unroll 1
  for (int s = 0; s < S_; ++s) {
    // ---- stage 1: frags feed W2,W3 (qq row 0) and W6 (k row 1) ----
    if (m1) {
      f0 = *(const f16x8*)&A1[rd0];
      f1 = *(const f16x8*)&A1[rd0 + 32];
      f2 = *(const f16x8*)&A1[rd0 + 64];
      f3 = *(const f16x8*)&A1[rd0 + 96];
    }

    // next step's table gathers + s+2 idx: only q0 consumes them -> masked
    const int s2 = (s + 2 < S_) ? (s + 2) : (S_ - 1);
    if (st) {
      ninT = C1[nic * E_ + e] + SD1[nisd * E_ + e];
      nsd6 = SD6[nisd * E_ + e];
      na4 = nia ? A4t1 : A4t0;
      na5 = nia ? A5t1 : A5t0;
      na6 = nia ? A6t1 : A6t0;
      ntg  = C1[nict * E_ + e] + SD1[nist * E_ + e];
      const int4 iv = *(const int4*)&idx_lds[s2][0];
      nic = iv.x; nisd = iv.y; nia = iv.z; nict = iv.w;
      nist = idx_lds[s2][4];
    }

    acc2[0] = b2e;
    acc3[0] = b3e;
    acc6[1] = a6v + sd6v;                 // k row 1 -> D reg1
    acc2 = __builtin_amdgcn_mfma_f32_16x16x32_f16(f0, w2f[0], acc2, 0, 0, 0);
    acc3 = __builtin_amdgcn_mfma_f32_16x16x32_f16(f0, w3f[0], acc3, 0, 0, 0);
    acc6 = __builtin_amdgcn_mfma_f32_16x16x32_f16(f0, w6f[0], acc6, 0, 0, 0);
    acc2 = __builtin_amdgcn_mfma_f32_16x16x32_f16(f1, w2f[1], acc2, 0, 0, 0);
    acc3 = __builtin_amdgcn_mfma_f32_16x16x32_f16(f1, w3f[1], acc3, 0, 0, 0);
    acc6 = __builtin_amdgcn_mfma_f32_16x16x32_f16(f1, w6f[1], acc6, 0, 0, 0);
    acc2 = __builtin_amdgcn_mfma_f32_16x16x32_f16(f2, w2f[2], acc2, 0, 0, 0);
    acc3 = __builtin_amdgcn_mfma_f32_16x16x32_f16(f2, w3f[2], acc3, 0, 0, 0);
    acc6 = __builtin_amdgcn_mfma_f32_16x16x32_f16(f2, w6f[2], acc6, 0, 0, 0);
    acc2 = __builtin_amdgcn_mfma_f32_16x16x32_f16(f3, w2f[3], acc2, 0, 0, 0);
    acc3 = __builtin_amdgcn_mfma_f32_16x16x32_f16(f3, w3f[3], acc3, 0, 0, 0);
    acc6 = __builtin_amdgcn_mfma_f32_16x16x32_f16(f3, w6f[3], acc6, 0, 0, 0);

    // real values in quad 0 (row0 -> reg0, row1 -> reg1)
    const float g2  = fast_sigmoid(acc2[0]);
    const float th3 = fast_tanh(acc3[0]);
    const float g6  = fast_sigmoid(acc6[1]);
    const float sdfv = g2 * th3;
    if (st) A2[e] = (_Float16)sdfv;
    __syncthreads();                          // B1: sdf staged

    // ---- stage 2: W4, W5 on sdf (row 0 only) ----
    if (m2) {
      g0  = *(const f16x8*)&A2[rd0];
      g1  = *(const f16x8*)&A2[rd0 + 32];
      g2v = *(const f16x8*)&A2[rd0 + 64];
      g3  = *(const f16x8*)&A2[rd0 + 96];
    }

    acc4[0] = a4v;
    acc5[0] = a5v;
    acc4 = __builtin_amdgcn_mfma_f32_16x16x32_f16(g0, w4f[0], acc4, 0, 0, 0);
    acc5 = __builtin_amdgcn_mfma_f32_16x16x32_f16(g0, w5f[0], acc5, 0, 0, 0);
    acc4 = __builtin_amdgcn_mfma_f32_16x16x32_f16(g1, w4f[1], acc4, 0, 0, 0);
    acc5 = __builtin_amdgcn_mfma_f32_16x16x32_f16(g1, w5f[1], acc5, 0, 0, 0);
    acc4 = __builtin_amdgcn_mfma_f32_16x16x32_f16(g2v, w4f[2], acc4, 0, 0, 0);
    acc5 = __builtin_amdgcn_mfma_f32_16x16x32_f16(g2v, w5f[2], acc5, 0, 0, 0);
    acc4 = __builtin_amdgcn_mfma_f32_16x16x32_f16(g3, w4f[3], acc4, 0, 0, 0);
    acc5 = __builtin_amdgcn_mfma_f32_16x16x32_f16(g3, w5f[3], acc5, 0, 0, 0);

    const float pka  = fast_sigmoid(acc4[0]) * fast_tanh(acc5[0]);  // real in q0
    const float knew = pka + g6 * (kreg - pka);
    kreg = knew;
    if (st) {
      A1[e]      = (_Float16)(knew - ninT);   // next qq
      A1[RS + e] = (_Float16)knew;            // next k
    }

    // fused logit: dot(target, knew); DPP sum -> lane15 of each quad (q0 real)
    float p = tgt * knew;
    p = DPP_ADD(p, 0x111);
    p = DPP_ADD(p, 0x112);
    p = DPP_ADD(p, 0x114);
    p = DPP_ADD(p, 0x118);
    if (l15 == 15 && q == 0) red[w] = p;

    inT = ninT; sd6v = nsd6; a4v = na4; a5v = na5; a6v = na6; tgt = ntg;

    __syncthreads();                          // B2: A1' + red visible

    if (tid == 0) {
      float logit = 0.f;
      #pragma unroll
      for (int x = 0; x < 8; ++x) logit += red[x];
      olog[s] = fast_sigmoid(logit);
    }
  }

  // single coalesced output flush
  __syncthreads();
  for (int i = tid; i < S_; i += 512) out[bj * S_ + i] = olog[i];
}

extern "C" void kernel_launch(void* const* d_in, const int* in_sizes, int n_in,
                              void* d_out, int out_size, void* d_ws, size_t ws_size,
                              hipStream_t stream) {
  const int*   c         = (const int*)  d_in[0];
  const int*   sd        = (const int*)  d_in[1];
  const int*   a         = (const int*)  d_in[2];
  const int*   cshft     = (const int*)  d_in[3];
  const int*   sdshft    = (const int*)  d_in[4];
  const float* c_table   = (const float*)d_in[5];
  const float* sd_table  = (const float*)d_in[6];
  const float* a_table   = (const float*)d_in[7];
  const float* knowledge = (const float*)d_in[8];
  const float* W1 = (const float*)d_in[9];  const float* b1 = (const float*)d_in[10];
  const float* W2 = (const float*)d_in[11]; const float* b2 = (const float*)d_in[12];
  const float* W3 = (const float*)d_in[13]; const float* b3 = (const float*)d_in[14];
  const float* W4 = (const float*)d_in[15]; const float* b4 = (const float*)d_in[16];
  const float* W5 = (const float*)d_in[17]; const float* b5 = (const float*)d_in[18];
  const float* W6 = (const float*)d_in[19]; const float* b6 = (const float*)d_in[20];
  float* ws  = (float*)d_ws;
  float* out = (float*)d_out;
  (void)in_sizes; (void)n_in; (void)out_size; (void)ws_size;

  dimkt_prep<<<158, 256, 0, stream>>>(c_table, sd_table, a_table,
                                      W1, b1, W4, b4, W5, b5, W6, b6, ws);
  dimkt_scan<<<512, 512, 0, stream>>>(c, sd, a, cshft, sdshft, knowledge,
                                      W2, b2, W3, b3, W4, W5, W6, ws, out);
}

// Round 10
// 260.687 us; speedup vs baseline: 6.0831x; 1.8812x over previous
//
#include <hip/hip_runtime.h>

// DIMKT forward. B=512, S=200, E=128.
// dimkt_prep: 158 blocks x 256 thr; table rows folded through W halves.
//   ws layout (floats): C1=0, SD1=131200, SD6=144256, A4=157312, A5=157568,
//   A6=157824.
// dimkt_scan: 256 blocks x 512 thr, 2 batch rows/block (r6 decomposition —
//   measured-best; step-wall is decomposition-invariant, so shrink the wall):
//   * in-loop barriers are `s_waitcnt lgkmcnt(0); s_barrier` (NO vmcnt drain —
//     table gathers stay in flight across B1, drained at their pre-B2 use)
//   * MFMA chains ordered acc2,acc3 first so sigmoid/tanh/sdf-store overlap
//     acc6 MFMA issue; g6 sigmoid moved after B1 (overlaps g-frag ds_read)
//   * logit: per-wave DPP partials -> part[] LDS AFTER B2 (no mid-loop reader,
//     overlaps next stage1); single cross-wave reduce after the loop
//   Tile rows: {0,8}=qq, {1,9}=k (stage1: W2,W3 -> D reg0; W6 -> D reg1; all
//   real values in quads 0/2), {0,8}=sdf (stage2). Weights as VGPR B-frags.
//   Masked frag reads with persistent zero frags; indices LDS-preloaded.

#define S_ 200
#define E_ 128
#define RS 136   // halves per LDS row

typedef float  float4v __attribute__((ext_vector_type(4)));
typedef _Float16 f16x8 __attribute__((ext_vector_type(8)));

// workgroup barrier with LDS-only drain: leaves vmcnt in flight
#define BAR() asm volatile("s_waitcnt lgkmcnt(0)\n\ts_barrier" ::: "memory")

__device__ __forceinline__ float fast_sigmoid(float x) {
  return __builtin_amdgcn_rcpf(1.f + __expf(-x));
}
__device__ __forceinline__ float fast_tanh(float x) {
  return 2.f * __builtin_amdgcn_rcpf(1.f + __expf(-2.f * x)) - 1.f;
}

// x + row_shr:<ctrl> shifted x (bound_ctrl: zeros in); sum lands in lane15 of each 16-row
#define DPP_ADD(x, ctrl) \
  ((x) + __builtin_bit_cast(float, __builtin_amdgcn_update_dpp( \
       0, __builtin_bit_cast(int, (x)), (ctrl), 0xf, 0xf, true)))

__device__ __forceinline__ f16x8 cvt8(const float* __restrict__ p) {
  float4v a = *(const float4v*)p;
  float4v b = *(const float4v*)(p + 4);
  f16x8 r;
  r[0] = (_Float16)a[0]; r[1] = (_Float16)a[1];
  r[2] = (_Float16)a[2]; r[3] = (_Float16)a[3];
  r[4] = (_Float16)b[0]; r[5] = (_Float16)b[1];
  r[6] = (_Float16)b[2]; r[7] = (_Float16)b[3];
  return r;
}

// ---------------- prep: 8 rows/block, coalesced LDS-staged W ----------------
__global__ __launch_bounds__(256) void dimkt_prep(
    const float* __restrict__ c_table, const float* __restrict__ sd_table,
    const float* __restrict__ a_table,
    const float* __restrict__ W1, const float* __restrict__ b1,
    const float* __restrict__ W4, const float* __restrict__ b4,
    const float* __restrict__ W5, const float* __restrict__ b5,
    const float* __restrict__ W6, const float* __restrict__ b6,
    float* __restrict__ ws) {
  __shared__ __attribute__((aligned(16))) float s_src[8][E_];
  __shared__ float s_w[E_][33];
  const int blk = blockIdx.x, t = threadIdx.x;
  const int e = t & 127, h = t >> 7;
  const float* src; const float* wb; const float* bias; float* dst;
  int r0, maxrow, wstr, woff;
  if (blk < 129)      { r0 = blk * 8;       src = c_table;  maxrow = 1024; wb = W1; wstr = 256; woff = 0;   bias = nullptr; dst = ws; }
  else if (blk < 142) { r0 = (blk-129) * 8; src = sd_table; maxrow = 101;  wb = W1; wstr = 256; woff = 128; bias = b1;      dst = ws + 131200; }
  else if (blk < 155) { r0 = (blk-142) * 8; src = sd_table; maxrow = 101;  wb = W6; wstr = 384; woff = 256; bias = nullptr; dst = ws + 144256; }
  else if (blk == 155){ r0 = 0;             src = a_table;  maxrow = 1;    wb = W4; wstr = 256; woff = 128; bias = b4;      dst = ws + 157312; }
  else if (blk == 156){ r0 = 0;             src = a_table;  maxrow = 1;    wb = W5; wstr = 256; woff = 128; bias = b5;      dst = ws + 157568; }
  else                { r0 = 0;             src = a_table;  maxrow = 1;    wb = W6; wstr = 384; woff = 128; bias = b6;      dst = ws + 157824; }
  #pragma unroll
  for (int i = 0; i < 4; ++i) {
    int idx = i * 256 + t, row = idx >> 7, col = idx & 127;
    int rr = r0 + row; if (rr > maxrow) rr = maxrow;
    s_src[row][col] = src[rr * E_ + col];
  }
  float binit = bias ? bias[e] : 0.f;
  float acc[4] = {binit, binit, binit, binit};
  for (int k0 = 0; k0 < 4; ++k0) {
    __syncthreads();                 // first: s_src ready; later: s_w reuse safe
    #pragma unroll
    for (int i = 0; i < 16; ++i) {
      int idx = i * 256 + t;
      s_w[idx >> 5][idx & 31] = wb[(idx >> 5) * wstr + woff + k0 * 32 + (idx & 31)];
    }
    __syncthreads();
    #pragma unroll 4
    for (int kk = 0; kk < 32; ++kk) {
      float wv = s_w[e][kk];
      #pragma unroll
      for (int g = 0; g < 4; ++g)
        acc[g] += wv * s_src[h * 4 + g][k0 * 32 + kk];
    }
  }
  #pragma unroll
  for (int g = 0; g < 4; ++g) {
    int row = r0 + h * 4 + g;
    if (row <= maxrow) dst[row * E_ + e] = acc[g];
  }
}

// ---------------- the scan ----------------
__global__ __launch_bounds__(512, 2) void dimkt_scan(
    const int* __restrict__ c, const int* __restrict__ sd, const int* __restrict__ a,
    const int* __restrict__ cshft, const int* __restrict__ sdshft,
    const float* __restrict__ knowledge,
    const float* __restrict__ W2, const float* __restrict__ b2,
    const float* __restrict__ W3, const float* __restrict__ b3,
    const float* __restrict__ W4, const float* __restrict__ W5,
    const float* __restrict__ W6,
    const float* __restrict__ ws, float* __restrict__ out) {

  const float* __restrict__ C1  = ws;
  const float* __restrict__ SD1 = ws + 131200;
  const float* __restrict__ SD6 = ws + 144256;
  const float* __restrict__ A4  = ws + 157312;
  const float* __restrict__ A5  = ws + 157568;
  const float* __restrict__ A6  = ws + 157824;

  const int tid  = threadIdx.x;
  const int w    = tid >> 6;        // wave 0..7 -> E-slice [16w, 16w+16)
  const int lane = tid & 63;
  const int l15  = lane & 15;
  const int q    = lane >> 4;       // quad 0..3
  const int qodd = q & 1;
  const int e    = w * 16 + l15;    // output column this lane owns
  const int j    = q >> 1;          // batch row within block
  const int bj   = blockIdx.x * 2 + j;

  __shared__ __attribute__((aligned(16))) _Float16 A1[16 * RS];
  __shared__ __attribute__((aligned(16))) _Float16 A2[16 * RS];
  __shared__ __attribute__((aligned(32))) int idx_lds[S_][2][8];
  __shared__ float part[8][2][S_];

  // one-time coalesced index preload
  for (int i = tid; i < 2 * S_; i += 512) {
    const int jj = (i >= S_) ? 1 : 0;
    const int ss = jj ? (i - S_) : i;
    const int src = (blockIdx.x * 2 + jj) * S_ + ss;
    idx_lds[ss][jj][0] = c[src];
    idx_lds[ss][jj][1] = sd[src];
    idx_lds[ss][jj][2] = a[src];
    idx_lds[ss][jj][3] = cshft[src];
    idx_lds[ss][jj][4] = sdshft[src];
  }

  // tile rows: qq/sdf -> j*8 (0,8); k -> j*8+1 (1,9). Stores by even quads only.
  const int stq = (j * 8) * RS + e;
  const int stk = stq + RS;
  const int rd0 = l15 * RS + q * 8;   // A-frag read base (halves), +32*t per frag
  const bool m1 = (l15 & 6) == 0;     // rows {0,1,8,9} (stage 1)
  const bool m2 = (l15 & 7) == 0;     // rows {0,8}     (stage 2)

  // Weight B-fragments: lane holds W[e][32t + 8q + 0..7]
  f16x8 w2f[4], w3f[4], w4f[4], w5f[4], w6f[4];
  #pragma unroll
  for (int t = 0; t < 4; ++t) {
    const int ko = t * 32 + q * 8;
    w2f[t] = cvt8(W2 + e * 128 + ko);
    w3f[t] = cvt8(W3 + e * 128 + ko);
    w4f[t] = cvt8(W4 + e * 256 + ko);   // first E cols
    w5f[t] = cvt8(W5 + e * 256 + ko);
    w6f[t] = cvt8(W6 + e * 384 + ko);   // k third of W6
  }
  const float b2e = b2[e], b3e = b3[e];
  const float A4t0 = A4[e], A4t1 = A4[E_ + e];
  const float A5t0 = A5[e], A5t1 = A5[E_ + e];
  const float A6t0 = A6[e], A6t1 = A6[E_ + e];

  float kreg = knowledge[e];

  // pre-loop gathers (outside steady loop)
  const int base = bj * S_;
  int ic = c[base], isd = sd[base], ia = a[base], ict = cshft[base], ist = sdshft[base];
  float inT  = C1[ic * E_ + e] + SD1[isd * E_ + e];
  float sd6v = SD6[isd * E_ + e];
  float a4v = ia ? A4t1 : A4t0;
  float a5v = ia ? A5t1 : A5t0;
  float a6v = ia ? A6t1 : A6t0;
  float tgt  = C1[ict * E_ + e] + SD1[ist * E_ + e];
  int nic = c[base + 1], nisd = sd[base + 1], nia = a[base + 1],
      nict = cshft[base + 1], nist = sdshft[base + 1];

  __syncthreads();                         // idx preload visible
  if (!qodd) {
    A1[stq] = (_Float16)(kreg - inT);      // qq row
    A1[stk] = (_Float16)kreg;              // k row
  }
  __syncthreads();                         // initial A1 staged

  // persistent zero frags: masked-out lanes never write them -> stay 0
  f16x8 f0{}, f1{}, f2{}, f3{};
  f16x8 g0{}, g1{}, g2v{}, g3{};

  // persistent accumulators; unused regs carry bounded stale values.
  float4v acc2{0.f,0.f,0.f,0.f}, acc3{0.f,0.f,0.f,0.f}, acc6{0.f,0.f,0.f,0.f};
  float4v acc4{0.f,0.f,0.f,0.f}, acc5{0.f,0.f,0.f,0.f};

  float pprev = 0.f;                       // previous step's logit product
  int   sprev = 0;

  #pragma unroll 1
  for (int s = 0; s < S_; ++s) {
    // ---- stage 1: frags feed W2,W3 (qq rows 0,8) and W6 (k rows 1,9) ----
    if (m1) {
      f0 = *(const f16x8*)&A1[rd0];
      f1 = *(const f16x8*)&A1[rd0 + 32];
      f2 = *(const f16x8*)&A1[rd0 + 64];
      f3 = *(const f16x8*)&A1[rd0 + 96];
    }

    // previous step's logit reduction (after B2 — no one reads part[] mid-loop;
    // overlaps this stage's ds_read latency / MFMA issue)
    if (s > 0) {
      float pr = pprev;
      pr = DPP_ADD(pr, 0x111);
      pr = DPP_ADD(pr, 0x112);
      pr = DPP_ADD(pr, 0x114);
      pr = DPP_ADD(pr, 0x118);
      if (l15 == 15 && !qodd) part[w][j][sprev] = pr;
    }

    // next step's table gathers: in flight across B1 (no vmcnt drain there),
    // consumed (vmcnt-waited) just before the A1 write at end of stage 2.
    float ninT = C1[nic * E_ + e] + SD1[nisd * E_ + e];
    float nsd6 = SD6[nisd * E_ + e];
    float na4 = nia ? A4t1 : A4t0;
    float na5 = nia ? A5t1 : A5t0;
    float na6 = nia ? A6t1 : A6t0;
    float ntg  = C1[nict * E_ + e] + SD1[nist * E_ + e];

    // s+2 indices from LDS (lgkm; broadcast)
    const int s2 = (s + 2 < S_) ? (s + 2) : (S_ - 1);
    const int4 iv = *(const int4*)&idx_lds[s2][j][0];
    const int tist = idx_lds[s2][j][4];

    // acc2 and acc3 chains first -> their transcendentals + sdf store overlap
    // the acc6 MFMA issue (separate MFMA/VALU pipes)
    acc2[0] = b2e;
    acc3[0] = b3e;
    acc2 = __builtin_amdgcn_mfma_f32_16x16x32_f16(f0, w2f[0], acc2, 0, 0, 0);
    acc3 = __builtin_amdgcn_mfma_f32_16x16x32_f16(f0, w3f[0], acc3, 0, 0, 0);
    acc2 = __builtin_amdgcn_mfma_f32_16x16x32_f16(f1, w2f[1], acc2, 0, 0, 0);
    acc3 = __builtin_amdgcn_mfma_f32_16x16x32_f16(f1, w3f[1], acc3, 0, 0, 0);
    acc2 = __builtin_amdgcn_mfma_f32_16x16x32_f16(f2, w2f[2], acc2, 0, 0, 0);
    acc3 = __builtin_amdgcn_mfma_f32_16x16x32_f16(f2, w3f[2], acc3, 0, 0, 0);
    acc2 = __builtin_amdgcn_mfma_f32_16x16x32_f16(f3, w2f[3], acc2, 0, 0, 0);
    acc3 = __builtin_amdgcn_mfma_f32_16x16x32_f16(f3, w3f[3], acc3, 0, 0, 0);

    acc6[1] = a6v + sd6v;                 // k rows 1,9 -> D reg1
    acc6 = __builtin_amdgcn_mfma_f32_16x16x32_f16(f0, w6f[0], acc6, 0, 0, 0);
    acc6 = __builtin_amdgcn_mfma_f32_16x16x32_f16(f1, w6f[1], acc6, 0, 0, 0);

    const float g2  = fast_sigmoid(acc2[0]);   // overlaps acc6 MFMA issue
    const float th3 = fast_tanh(acc3[0]);
    const float sdfv = g2 * th3;
    if (!qodd) A2[stq] = (_Float16)sdfv;

    acc6 = __builtin_amdgcn_mfma_f32_16x16x32_f16(f2, w6f[2], acc6, 0, 0, 0);
    acc6 = __builtin_amdgcn_mfma_f32_16x16x32_f16(f3, w6f[3], acc6, 0, 0, 0);

    BAR();                                     // B1: sdf staged (lgkm only)

    // ---- stage 2: W4, W5 on sdf (rows 0,8 only) ----
    if (m2) {
      g0  = *(const f16x8*)&A2[rd0];
      g1  = *(const f16x8*)&A2[rd0 + 32];
      g2v = *(const f16x8*)&A2[rd0 + 64];
      g3  = *(const f16x8*)&A2[rd0 + 96];
    }

    const float g6 = fast_sigmoid(acc6[1]);    // overlaps g-frag ds_read

    acc4[0] = a4v;
    acc4 = __builtin_amdgcn_mfma_f32_16x16x32_f16(g0, w4f[0], acc4, 0, 0, 0);
    acc4 = __builtin_amdgcn_mfma_f32_16x16x32_f16(g1, w4f[1], acc4, 0, 0, 0);
    acc4 = __builtin_amdgcn_mfma_f32_16x16x32_f16(g2v, w4f[2], acc4, 0, 0, 0);
    acc4 = __builtin_amdgcn_mfma_f32_16x16x32_f16(g3, w4f[3], acc4, 0, 0, 0);
    acc5[0] = a5v;
    acc5 = __builtin_amdgcn_mfma_f32_16x16x32_f16(g0, w5f[0], acc5, 0, 0, 0);
    acc5 = __builtin_amdgcn_mfma_f32_16x16x32_f16(g1, w5f[1], acc5, 0, 0, 0);

    const float s4 = fast_sigmoid(acc4[0]);    // overlaps acc5 MFMA issue

    acc5 = __builtin_amdgcn_mfma_f32_16x16x32_f16(g2v, w5f[2], acc5, 0, 0, 0);
    acc5 = __builtin_amdgcn_mfma_f32_16x16x32_f16(g3, w5f[3], acc5, 0, 0, 0);

    const float t5  = fast_tanh(acc5[0]);
    const float pka = s4 * t5;                 // real in even quads
    const float knew = pka + g6 * (kreg - pka);
    kreg = knew;
    if (!qodd) {
      A1[stq] = (_Float16)(knew - ninT);       // next qq (vmcnt wait lands here)
      A1[stk] = (_Float16)knew;                // next k
    }

    pprev = tgt * knew;                        // logit product; reduced after B2
    sprev = s;

    inT = ninT; sd6v = nsd6; a4v = na4; a5v = na5; a6v = na6; tgt = ntg;
    nic = iv.x; nisd = iv.y; nia = iv.z; nict = iv.w; nist = tist;

    BAR();                                     // B2: A1' staged (lgkm only)
  }

  // last step's logit partial
  {
    float pr = pprev;
    pr = DPP_ADD(pr, 0x111);
    pr = DPP_ADD(pr, 0x112);
    pr = DPP_ADD(pr, 0x114);
    pr = DPP_ADD(pr, 0x118);
    if (l15 == 15 && !qodd) part[w][j][sprev] = pr;
  }

  // final cross-wave reduce + sigmoid + store
  __syncthreads();
  for (int i = tid; i < 2 * S_; i += 512) {
    const int jj = (i >= S_) ? 1 : 0;
    const int ss = jj ? (i - S_) : i;
    float logit = 0.f;
    #pragma unroll
    for (int x = 0; x < 8; ++x) logit += part[x][jj][ss];
    out[(blockIdx.x * 2 + jj) * S_ + ss] = fast_sigmoid(logit);
  }
}

extern "C" void kernel_launch(void* const* d_in, const int* in_sizes, int n_in,
                              void* d_out, int out_size, void* d_ws, size_t ws_size,
                              hipStream_t stream) {
  const int*   c         = (const int*)  d_in[0];
  const int*   sd        = (const int*)  d_in[1];
  const int*   a         = (const int*)  d_in[2];
  const int*   cshft     = (const int*)  d_in[3];
  const int*   sdshft    = (const int*)  d_in[4];
  const float* c_table   = (const float*)d_in[5];
  const float* sd_table  = (const float*)d_in[6];
  const float* a_table   = (const float*)d_in[7];
  const float* knowledge = (const float*)d_in[8];
  const float* W1 = (const float*)d_in[9];  const float* b1 = (const float*)d_in[10];
  const float* W2 = (const float*)d_in[11]; const float* b2 = (const float*)d_in[12];
  const float* W3 = (const float*)d_in[13]; const float* b3 = (const float*)d_in[14];
  const float* W4 = (const float*)d_in[15]; const float* b4 = (const float*)d_in[16];
  const float* W5 = (const float*)d_in[17]; const float* b5 = (const float*)d_in[18];
  const float* W6 = (const float*)d_in[19]; const float* b6 = (const float*)d_in[20];
  float* ws  = (float*)d_ws;
  float* out = (float*)d_out;
  (void)in_sizes; (void)n_in; (void)out_size; (void)ws_size;

  dimkt_prep<<<158, 256, 0, stream>>>(c_table, sd_table, a_table,
                                      W1, b1, W4, b4, W5, b5, W6, b6, ws);
  dimkt_scan<<<256, 512, 0, stream>>>(c, sd, a, cshft, sdshft, knowledge,
                                      W2, b2, W3, b3, W4, W5, W6, ws, out);
}